// Round 12
// baseline (456.591 us; speedup 1.0000x reference)
//
#include <hip/hip_runtime.h>
#include <hip/hip_cooperative_groups.h>

namespace cg = cooperative_groups;

#define D_FEAT 32
#define RSH 8              // 256 nodes per range
#define RS_NODES 256
#define LOCAL_SHIFT 24     // pack: src | (dst&255)<<24  (needs N <= 2^24)
#define SRC_MASK 0x00FFFFFFu
#define NR_PAD 512         // scan width / max ranges (N <= 131072)
#define CH_MAX 2048        // edges staged per sub-chunk in LDS
#define MAXG 2048          // target cooperative grid

struct BinSmem {
    unsigned sedge[CH_MAX];
    unsigned short skey[CH_MAX];
    unsigned hist[NR_PAD];
    unsigned base_l[NR_PAD];
};
struct BldSmem {
    unsigned sc[2][NR_PAD];
    unsigned deg_l[RS_NODES];
    unsigned cur_l[RS_NODES];
    float sinv[RS_NODES];
    unsigned wtot[4];
};
union MegaSmem { BinSmem bin; BldSmem bld; };

// round-to-nearest-even bf16 pack of two floats
__device__ __forceinline__ unsigned bfpack(float lo, float hi) {
    unsigned ul = __float_as_uint(lo), uh = __float_as_uint(hi);
    ul = (ul + 0x7FFFu + ((ul >> 16) & 1u)) >> 16;
    uh = (uh + 0x7FFFu + ((uh >> 16) & 1u)) >> 16;
    return ul | (uh << 16);
}

__device__ __forceinline__ void bfadd(float4& a, uint2 w) {
    a.x += __uint_as_float(w.x << 16);
    a.y += __uint_as_float(w.x & 0xFFFF0000u);
    a.z += __uint_as_float(w.y << 16);
    a.w += __uint_as_float(w.y & 0xFFFF0000u);
}

// ---- phase 1: fused binning (stage chunk in LDS, hist, block-reserve, place) ----
__device__ void binfuse_block(BinSmem& s, const int* __restrict__ src, const int* __restrict__ dst,
                              unsigned* __restrict__ cnt, unsigned* __restrict__ binned,
                              int NR, int CAP, int lo, int hi) {
    for (int base = lo; base < hi; base += CH_MAX) {
        int n = min(CH_MAX, hi - base);
        for (int i = threadIdx.x; i < NR; i += blockDim.x) s.hist[i] = 0u;
        __syncthreads();
        int nq = n >> 2;
        const int4* ps = (const int4*)(src + base);
        const int4* pd = (const int4*)(dst + base);
        for (int qi = threadIdx.x; qi < nq; qi += blockDim.x) {
            int4 sv = ps[qi];
            int4 dv = pd[qi];
            int i0 = qi << 2;
            unsigned r0 = (unsigned)dv.x >> RSH, r1 = (unsigned)dv.y >> RSH;
            unsigned r2 = (unsigned)dv.z >> RSH, r3 = (unsigned)dv.w >> RSH;
            s.sedge[i0 + 0] = (unsigned)sv.x | ((unsigned)(dv.x & (RS_NODES - 1)) << LOCAL_SHIFT);
            s.sedge[i0 + 1] = (unsigned)sv.y | ((unsigned)(dv.y & (RS_NODES - 1)) << LOCAL_SHIFT);
            s.sedge[i0 + 2] = (unsigned)sv.z | ((unsigned)(dv.z & (RS_NODES - 1)) << LOCAL_SHIFT);
            s.sedge[i0 + 3] = (unsigned)sv.w | ((unsigned)(dv.w & (RS_NODES - 1)) << LOCAL_SHIFT);
            s.skey[i0 + 0] = (unsigned short)r0;
            s.skey[i0 + 1] = (unsigned short)r1;
            s.skey[i0 + 2] = (unsigned short)r2;
            s.skey[i0 + 3] = (unsigned short)r3;
            atomicAdd(&s.hist[r0], 1u);
            atomicAdd(&s.hist[r1], 1u);
            atomicAdd(&s.hist[r2], 1u);
            atomicAdd(&s.hist[r3], 1u);
        }
        for (int i = (nq << 2) + threadIdx.x; i < n; i += blockDim.x) {
            int sv = src[base + i], dv = dst[base + i];
            unsigned r = (unsigned)dv >> RSH;
            s.sedge[i] = (unsigned)sv | ((unsigned)(dv & (RS_NODES - 1)) << LOCAL_SHIFT);
            s.skey[i] = (unsigned short)r;
            atomicAdd(&s.hist[r], 1u);
        }
        __syncthreads();
        // reserve: one global atomic per (block,range); base_l becomes the live cursor
        for (int r = threadIdx.x; r < NR; r += blockDim.x) {
            unsigned c = s.hist[r];
            s.base_l[r] = c ? atomicAdd(&cnt[r], c) : 0u;
        }
        __syncthreads();
        // place via LDS cursor
        for (int i = threadIdx.x; i < n; i += blockDim.x) {
            unsigned r = s.skey[i];
            unsigned off = atomicAdd(&s.base_l[r], 1u);
            if (off < (unsigned)CAP)  // safety clamp (CAP has ~30 sigma headroom)
                binned[(size_t)r * CAP + off] = s.sedge[i];
        }
        __syncthreads();
    }
}

// ---- phase 2: per-range CSR build + dense offsets + wf bf16 conversion ----
__device__ void build_block(BldSmem& s, const unsigned* __restrict__ binned,
                            const unsigned* __restrict__ cnt, const float* __restrict__ feat,
                            unsigned* __restrict__ wf, unsigned* __restrict__ csr,
                            uint2* __restrict__ ni, int N, int E, int NR, int CAP, int r) {
    int tid = threadIdx.x;  // 256
    s.sc[0][tid]       = (tid < NR)       ? min(cnt[tid], (unsigned)CAP)       : 0u;
    s.sc[0][tid + 256] = (tid + 256 < NR) ? min(cnt[tid + 256], (unsigned)CAP) : 0u;
    int pin = 0;
    for (int off = 1; off < NR_PAD; off <<= 1) {
        __syncthreads();
        int po = pin ^ 1;
        #pragma unroll
        for (int k = 0; k < 2; k++) {
            int idx = tid + k * 256;
            unsigned x = s.sc[pin][idx];
            if (idx >= off) x += s.sc[pin][idx - off];
            s.sc[po][idx] = x;
        }
        pin ^= 1;
    }
    __syncthreads();
    unsigned dense0 = (r == 0) ? 0u : s.sc[pin][r - 1];
    unsigned cntr = min(cnt[r], (unsigned)CAP);
    size_t seg = (size_t)r * CAP;
    s.deg_l[tid] = 0u;
    __syncthreads();
    for (unsigned e = tid; e < cntr; e += RS_NODES)
        atomicAdd(&s.deg_l[binned[seg + e] >> LOCAL_SHIFT], 1u);
    __syncthreads();
    unsigned d = s.deg_l[tid];
    int lane = tid & 63, w = tid >> 6;
    unsigned incl = d;
    #pragma unroll
    for (int off = 1; off < 64; off <<= 1) {
        unsigned t = __shfl_up(incl, off, 64);
        if (lane >= off) incl += t;
    }
    if (lane == 63) s.wtot[w] = incl;
    __syncthreads();
    unsigned woff = 0;
    #pragma unroll
    for (int i = 0; i < 4; i++) if (i < w) woff += s.wtot[i];
    unsigned base = dense0 + woff + incl - d;
    s.cur_l[tid] = base;
    float ivv = rsqrtf(1.0f + (float)d);
    s.sinv[tid] = ivv;
    int node = r * RS_NODES + tid;
    if (node < N) ni[node] = make_uint2(base, __float_as_uint(ivv));
    if (r == 0 && tid == 0) ni[N] = make_uint2((unsigned)E, 0u);
    __syncthreads();
    for (unsigned e = tid; e < cntr; e += RS_NODES) {
        unsigned p = binned[seg + e];
        unsigned pos = atomicAdd(&s.cur_l[p >> LOCAL_SHIFT], 1u);
        csr[pos] = p & SRC_MASK;
    }
    for (int i = tid; i < RS_NODES * 4; i += RS_NODES) {
        int nl = i >> 2, q = i & 3;
        int nn = r * RS_NODES + nl;
        if (nn < N) {
            float iw = s.sinv[nl];
            const float4* fp = (const float4*)(feat + (size_t)nn * D_FEAT + q * 8);
            float4 a = fp[0], b = fp[1];
            uint4 o;
            o.x = bfpack(iw * a.x, iw * a.y);
            o.y = bfpack(iw * a.z, iw * a.w);
            o.z = bfpack(iw * b.x, iw * b.y);
            o.w = bfpack(iw * b.z, iw * b.w);
            ((uint4*)wf)[(size_t)nn * 4 + q] = o;
        }
    }
    __syncthreads();
}

// ---- phase 3: persistent gather (identical body to round 10/11) ----
__device__ void gather_phase(const unsigned* __restrict__ wf, const unsigned* __restrict__ csr,
                             const uint2* __restrict__ ni, float* __restrict__ out,
                             int N, int per) {
    int w = blockIdx.x * (blockDim.x >> 6) + (threadIdx.x >> 6);
    int lane = threadIdx.x & 63;
    int g = lane >> 3;
    int q = lane & 7;
    int n0 = w * per;
    int n1 = min(N, n0 + per);
    if (n0 >= n1) return;
    uint2 cur = ni[n0];
    for (int node = n0; node < n1; ++node) {
        uint2 nxt = ni[node + 1];
        unsigned start = cur.x, end = nxt.x;
        float iv = __uint_as_float(cur.y);
        float4 acc = make_float4(0.f, 0.f, 0.f, 0.f);
        uint2 ws = *(const uint2*)(wf + (size_t)node * 16 + q * 2);
        if (g == 0) bfadd(acc, ws);
        unsigned k0 = start + g, k1 = start + 8 + g;
        unsigned j0 = (k0 < end) ? csr[k0] : (unsigned)node;
        unsigned j1 = (k1 < end) ? csr[k1] : (unsigned)node;
        uint2 w0 = *(const uint2*)(wf + (size_t)j0 * 16 + q * 2);
        uint2 w1 = *(const uint2*)(wf + (size_t)j1 * 16 + q * 2);
        if (k0 < end) bfadd(acc, w0);
        if (k1 < end) bfadd(acc, w1);
        unsigned k = start + 16 + g;
        if (k < end) {
            for (; k + 8 < end; k += 16) {
                unsigned ja = csr[k], jb = csr[k + 8];
                uint2 wa = *(const uint2*)(wf + (size_t)ja * 16 + q * 2);
                uint2 wb = *(const uint2*)(wf + (size_t)jb * 16 + q * 2);
                bfadd(acc, wa);
                bfadd(acc, wb);
            }
            if (k < end) {
                unsigned jc = csr[k];
                uint2 wc = *(const uint2*)(wf + (size_t)jc * 16 + q * 2);
                bfadd(acc, wc);
            }
        }
        #pragma unroll
        for (int off = 8; off < 64; off <<= 1) {
            acc.x += __shfl_xor(acc.x, off);
            acc.y += __shfl_xor(acc.y, off);
            acc.z += __shfl_xor(acc.z, off);
            acc.w += __shfl_xor(acc.w, off);
        }
        if (g == 0) {
            float4 rv;
            rv.x = iv * acc.x; rv.y = iv * acc.y; rv.z = iv * acc.z; rv.w = iv * acc.w;
            *(float4*)(out + (size_t)node * D_FEAT + q * 4) = rv;
        }
        cur = nxt;
    }
}

// ---- the fused cooperative kernel ----
__global__ void __launch_bounds__(256, 8)
mega_kernel(const int* src, const int* dst, const float* feat,
            unsigned* cnt, unsigned* binned, unsigned* csr, unsigned* wf, uint2* ni,
            float* out, int N, int E, int NR, int CAP, int chunk, int per) {
    __shared__ MegaSmem sm;
    cg::grid_group grid = cg::this_grid();
    // phase 0: zero cnt
    for (int i = blockIdx.x * blockDim.x + threadIdx.x; i < NR; i += gridDim.x * blockDim.x)
        cnt[i] = 0u;
    grid.sync();
    // phase 1: binning
    {
        int lo = blockIdx.x * chunk;
        int hi = min(E, lo + chunk);
        if (lo < hi) binfuse_block(sm.bin, src, dst, cnt, binned, NR, CAP, lo, hi);
    }
    grid.sync();
    // phase 2: build
    for (int r = blockIdx.x; r < NR; r += gridDim.x)
        build_block(sm.bld, binned, cnt, feat, wf, csr, ni, N, E, NR, CAP, r);
    grid.sync();
    // phase 3: gather
    gather_phase(wf, csr, ni, out, N, per);
}

// ---- standalone versions (fallback if cooperative launch unavailable) ----
__global__ void binfuse_kernel(const int* __restrict__ src, const int* __restrict__ dst,
                               unsigned* __restrict__ cnt, unsigned* __restrict__ binned,
                               int E, int NR, int CAP, int chunk) {
    __shared__ BinSmem s;
    int lo = blockIdx.x * chunk;
    int hi = min(E, lo + chunk);
    if (lo < hi) binfuse_block(s, src, dst, cnt, binned, NR, CAP, lo, hi);
}
__global__ void build_kernel(const unsigned* __restrict__ binned, const unsigned* __restrict__ cnt,
                             const float* __restrict__ feat, unsigned* __restrict__ wf,
                             unsigned* __restrict__ csr, uint2* __restrict__ ni,
                             int N, int E, int NR, int CAP) {
    __shared__ BldSmem s;
    build_block(s, binned, cnt, feat, wf, csr, ni, N, E, NR, CAP, blockIdx.x);
}
__global__ void gather_kernel(const unsigned* __restrict__ wf, const unsigned* __restrict__ csr,
                              const uint2* __restrict__ ni, float* __restrict__ out,
                              int N, int per) {
    gather_phase(wf, csr, ni, out, N, per);
}

// ---------- minimal fallback (atomic scatter) if workspace too small ----------
__global__ void fb_deg_kernel(const int* __restrict__ dst, float* __restrict__ deg, int E) {
    int i = blockIdx.x * blockDim.x + threadIdx.x;
    int stride = gridDim.x * blockDim.x;
    for (; i < E; i += stride) atomicAdd(&deg[dst[i]], 1.0f);
}
__global__ void fb_inv_kernel(const float* __restrict__ deg, float* __restrict__ inv, int N) {
    int i = blockIdx.x * blockDim.x + threadIdx.x;
    if (i < N) inv[i] = rsqrtf(1.0f + deg[i]);
}
__global__ void fb_scatter_kernel(const float* __restrict__ feat, const int* __restrict__ src,
                                  const int* __restrict__ dst, const float* __restrict__ inv,
                                  float* __restrict__ out, int E) {
    long long tid = (long long)blockIdx.x * blockDim.x + threadIdx.x;
    int e = (int)(tid >> 5);
    int d = (int)(tid & 31);
    if (e >= E) return;
    int s = src[e];
    int t = dst[e];
    atomicAdd(&out[t * D_FEAT + d], inv[s] * feat[s * D_FEAT + d]);
}
__global__ void fb_finalize_kernel(const float* __restrict__ feat, const float* __restrict__ inv,
                                   float* __restrict__ out, int ND) {
    int tid = blockIdx.x * blockDim.x + threadIdx.x;
    if (tid >= ND) return;
    float iv = inv[tid >> 5];
    out[tid] = iv * (out[tid] + iv * feat[tid]);
}

extern "C" void kernel_launch(void* const* d_in, const int* in_sizes, int n_in,
                              void* d_out, int out_size, void* d_ws, size_t ws_size,
                              hipStream_t stream) {
    const int* esrc = (const int*)d_in[1];
    const int* edst = (const int*)d_in[2];
    const float* feat = (const float*)d_in[0];
    float* out = (float*)d_out;

    const int N = in_sizes[0] / D_FEAT;
    const int E = in_sizes[1];
    const int ND = N * D_FEAT;
    const int NR = (N + RS_NODES - 1) >> RSH;

    // capacity-padded per-range segments: mean*1.5 + 256, rounded to 64
    int CAP = (E + NR - 1) / NR;
    CAP = CAP + CAP / 2 + 256;
    CAP = (CAP + 63) & ~63;

    // layout (words): cnt[NR] | binned[NR*CAP] | csr[E] | wf[16N] (16B-align) | ni[2(N+1)] (8B-align)
    size_t binned_off = NR;
    size_t csr_off = binned_off + (size_t)NR * CAP;
    size_t wf_off = (csr_off + (size_t)E + 3) & ~(size_t)3;
    size_t ni_off = (wf_off + 16 * (size_t)N + 1) & ~(size_t)1;
    size_t need = (ni_off + 2 * ((size_t)N + 1)) * 4;

    if (ws_size >= need && NR <= NR_PAD && N <= (1 << LOCAL_SHIFT)) {
        unsigned* ws_u   = (unsigned*)d_ws;
        unsigned* cnt    = ws_u;
        unsigned* binned = ws_u + binned_off;
        unsigned* csr    = ws_u + csr_off;
        unsigned* wf     = ws_u + wf_off;
        uint2*    ni     = (uint2*)(ws_u + ni_off);

        // size the cooperative grid from actual occupancy (host query; capture-time only)
        int occ = 0;
        hipError_t eo = hipOccupancyMaxActiveBlocksPerMultiprocessor(&occ, mega_kernel, 256, 0);
        bool coop = (eo == hipSuccess && occ > 0);
        if (coop) {
            int grid = occ * 256;           // 256 CUs on MI355X
            if (grid > MAXG) grid = MAXG;
            int chunk = (((E + grid - 1) / grid) + 3) & ~3;
            int per = (N + grid * 4 - 1) / (grid * 4);
            void* kargs[] = {
                (void*)&esrc, (void*)&edst, (void*)&feat,
                (void*)&cnt, (void*)&binned, (void*)&csr, (void*)&wf, (void*)&ni,
                (void*)&out, (void*)&N, (void*)&E, (void*)&NR, (void*)&CAP,
                (void*)&chunk, (void*)&per
            };
            hipError_t el = hipLaunchCooperativeKernel((void*)mega_kernel, dim3(grid), dim3(256),
                                                       kargs, 0, stream);
            if (el != hipSuccess) coop = false;
        }
        if (!coop) {
            hipMemsetAsync(cnt, 0, (size_t)NR * sizeof(unsigned), stream);
            {
                int grid = 512;
                int chunk = (((E + grid - 1) / grid) + 3) & ~3;
                binfuse_kernel<<<grid, 256, 0, stream>>>(esrc, edst, cnt, binned, E, NR, CAP, chunk);
            }
            build_kernel<<<NR, RS_NODES, 0, stream>>>(binned, cnt, feat, wf, csr, ni, N, E, NR, CAP);
            {
                int per = (N + MAXG * 4 - 1) / (MAXG * 4);
                gather_kernel<<<MAXG, 256, 0, stream>>>(wf, csr, ni, out, N, per);
            }
        }
    } else {
        float* deg = (float*)d_ws;
        float* inv = deg + N;
        hipMemsetAsync(deg, 0, (size_t)N * sizeof(float), stream);
        hipMemsetAsync(out, 0, (size_t)ND * sizeof(float), stream);
        {
            int grid = (E + 255) / 256; if (grid > 2048) grid = 2048;
            fb_deg_kernel<<<grid, 256, 0, stream>>>(edst, deg, E);
        }
        fb_inv_kernel<<<(N + 255) / 256, 256, 0, stream>>>(deg, inv, N);
        {
            long long total = (long long)E * D_FEAT;
            fb_scatter_kernel<<<(int)((total + 255) / 256), 256, 0, stream>>>(feat, esrc, edst, inv, out, E);
        }
        fb_finalize_kernel<<<(ND + 255) / 256, 256, 0, stream>>>(feat, inv, out, ND);
    }
}

// Round 13
// 104.205 us; speedup vs baseline: 4.3817x; 4.3817x over previous
//
#include <hip/hip_runtime.h>

#define D_FEAT 32
#define RSH 8              // 256 nodes per range
#define RS_NODES 256
#define LOCAL_SHIFT 24     // pack: src | (dst&255)<<24  (needs N <= 2^24)
#define SRC_MASK 0x00FFFFFFu
#define NR_PAD 512         // scan width / max ranges (N <= 131072)
#define BF_CHUNK 3328      // edges staged per binfuse block
#define GATHER_BLOCKS 2048 // persistent gather grid

// round-to-nearest-even bf16 pack of two floats
__device__ __forceinline__ unsigned bfpack(float lo, float hi) {
    unsigned ul = __float_as_uint(lo), uh = __float_as_uint(hi);
    ul = (ul + 0x7FFFu + ((ul >> 16) & 1u)) >> 16;
    uh = (uh + 0x7FFFu + ((uh >> 16) & 1u)) >> 16;
    return ul | (uh << 16);
}

__device__ __forceinline__ void bfadd(float4& a, uint2 w) {
    a.x += __uint_as_float(w.x << 16);
    a.y += __uint_as_float(w.x & 0xFFFF0000u);
    a.z += __uint_as_float(w.y << 16);
    a.w += __uint_as_float(w.y & 0xFFFF0000u);
}

// Fused single-pass binning (r11 proven): stage chunk in LDS, histogram by range,
// reserve per-range space with ONE global atomic per (block,range), place via LDS cursors
// into capacity-padded per-range segments binned[r*CAP ...].
__global__ void binfuse_kernel(const int* __restrict__ src, const int* __restrict__ dst,
                               unsigned* __restrict__ cnt,     // [NR], pre-zeroed
                               unsigned* __restrict__ binned,  // [NR*CAP]
                               int E, int NR, int CAP) {
    __shared__ unsigned sedge[BF_CHUNK];
    __shared__ unsigned short skey[BF_CHUNK];
    __shared__ unsigned hist[NR_PAD];
    __shared__ unsigned base_l[NR_PAD];
    int lo = blockIdx.x * BF_CHUNK;
    int n = min(BF_CHUNK, E - lo);
    if (n <= 0) return;
    for (int i = threadIdx.x; i < NR; i += blockDim.x) hist[i] = 0u;
    __syncthreads();
    for (int i = threadIdx.x; i < n; i += blockDim.x) {
        int s = src[lo + i];
        int d = dst[lo + i];
        sedge[i] = (unsigned)s | ((unsigned)(d & (RS_NODES - 1)) << LOCAL_SHIFT);
        unsigned r = (unsigned)d >> RSH;
        skey[i] = (unsigned short)r;
        atomicAdd(&hist[r], 1u);
    }
    __syncthreads();
    for (int r = threadIdx.x; r < NR; r += blockDim.x) {
        unsigned c = hist[r];
        base_l[r] = c ? atomicAdd(&cnt[r], c) : 0u;
    }
    __syncthreads();
    for (int i = threadIdx.x; i < NR; i += blockDim.x) hist[i] = 0u;
    __syncthreads();
    for (int i = threadIdx.x; i < n; i += blockDim.x) {
        unsigned r = skey[i];
        unsigned off = base_l[r] + atomicAdd(&hist[r], 1u);
        if (off < (unsigned)CAP)  // safety clamp (never triggers with 1.5x+ padding)
            binned[(size_t)r * CAP + off] = sedge[i];
    }
}

// Build per-node CSR within each 256-node range (r11 proven) + dense offsets + SPLIT
// bf16 conversion: wf_lo[n] = dims 0..15, wf_hi[n] = dims 16..31 (32B rows each).
__global__ void build_kernel(const unsigned* __restrict__ binned, const unsigned* __restrict__ cnt,
                             const float* __restrict__ feat,
                             unsigned* __restrict__ wf_lo, unsigned* __restrict__ wf_hi,
                             unsigned* __restrict__ csr, uint2* __restrict__ ni,
                             int N, int E, int NR, int CAP) {
    __shared__ unsigned sc[2][NR_PAD];
    __shared__ unsigned deg_l[RS_NODES];
    __shared__ unsigned cur_l[RS_NODES];
    __shared__ float sinv[RS_NODES];
    __shared__ unsigned wtot[4];
    int r = blockIdx.x;
    int tid = threadIdx.x;  // 256
    sc[0][tid]       = (tid < NR)       ? min(cnt[tid], (unsigned)CAP)       : 0u;
    sc[0][tid + 256] = (tid + 256 < NR) ? min(cnt[tid + 256], (unsigned)CAP) : 0u;
    int pin = 0;
    for (int off = 1; off < NR_PAD; off <<= 1) {
        __syncthreads();
        int po = pin ^ 1;
        #pragma unroll
        for (int k = 0; k < 2; k++) {
            int idx = tid + k * 256;
            unsigned x = sc[pin][idx];
            if (idx >= off) x += sc[pin][idx - off];
            sc[po][idx] = x;
        }
        pin ^= 1;
    }
    __syncthreads();
    unsigned dense0 = (r == 0) ? 0u : sc[pin][r - 1];
    unsigned cntr = min(cnt[r], (unsigned)CAP);
    size_t seg = (size_t)r * CAP;
    deg_l[tid] = 0u;
    __syncthreads();
    for (unsigned e = tid; e < cntr; e += RS_NODES)
        atomicAdd(&deg_l[binned[seg + e] >> LOCAL_SHIFT], 1u);
    __syncthreads();
    unsigned d = deg_l[tid];
    int lane = tid & 63, w = tid >> 6;
    unsigned incl = d;
    #pragma unroll
    for (int off = 1; off < 64; off <<= 1) {
        unsigned t = __shfl_up(incl, off, 64);
        if (lane >= off) incl += t;
    }
    if (lane == 63) wtot[w] = incl;
    __syncthreads();
    unsigned woff = 0;
    #pragma unroll
    for (int i = 0; i < 4; i++) if (i < w) woff += wtot[i];
    unsigned base = dense0 + woff + incl - d;
    cur_l[tid] = base;
    float ivv = rsqrtf(1.0f + (float)d);
    sinv[tid] = ivv;
    int node = r * RS_NODES + tid;
    if (node < N) ni[node] = make_uint2(base, __float_as_uint(ivv));
    if (r == 0 && tid == 0) ni[N] = make_uint2((unsigned)E, 0u);
    __syncthreads();
    for (unsigned e = tid; e < cntr; e += RS_NODES) {
        unsigned p = binned[seg + e];
        unsigned pos = atomicAdd(&cur_l[p >> LOCAL_SHIFT], 1u);
        csr[pos] = p & SRC_MASK;
    }
    // split wf conversion: quad q covers dims [8q, 8q+8) -> one uint4; q<2 -> lo, q>=2 -> hi
    for (int i = tid; i < RS_NODES * 4; i += RS_NODES) {
        int nl = i >> 2, q = i & 3;
        int nn = r * RS_NODES + nl;
        if (nn < N) {
            float iw = sinv[nl];
            const float4* fp = (const float4*)(feat + (size_t)nn * D_FEAT + q * 8);
            float4 a = fp[0], b = fp[1];
            uint4 o;
            o.x = bfpack(iw * a.x, iw * a.y);
            o.y = bfpack(iw * a.z, iw * a.w);
            o.z = bfpack(iw * b.x, iw * b.y);
            o.w = bfpack(iw * b.z, iw * b.w);
            unsigned* dest = (q < 2) ? wf_lo : wf_hi;
            ((uint4*)dest)[(size_t)nn * 2 + (q & 1)] = o;
        }
    }
}

// PERSISTENT half-feature gather: one pass over a 3.2MB wf half (fits per-XCD L2).
// 16 groups x 4 lanes; lane q covers dims [4q,4q+4) of this half via one uint2 per edge.
// 2 straight-line predicated slots cover deg<=32 (~99.98%); rare tail loop.
__global__ void gather_kernel(const unsigned* __restrict__ wfh, const unsigned* __restrict__ csr,
                              const uint2* __restrict__ ni, float* __restrict__ outh,
                              int N, int per) {
    int w = blockIdx.x * (blockDim.x >> 6) + (threadIdx.x >> 6);
    int lane = threadIdx.x & 63;
    int g = lane >> 2;   // edge slot within iteration (16 groups)
    int q = lane & 3;    // dim quad within half: [4q, 4q+4)
    int n0 = w * per;
    int n1 = min(N, n0 + per);
    if (n0 >= n1) return;
    uint2 cur = ni[n0];
    for (int node = n0; node < n1; ++node) {
        uint2 nxt = ni[node + 1];
        unsigned start = cur.x, end = nxt.x;
        float iv = __uint_as_float(cur.y);
        float4 acc = make_float4(0.f, 0.f, 0.f, 0.f);
        // self-loop from this wf half
        uint2 ws = *(const uint2*)(wfh + (size_t)node * 8 + q * 2);
        if (g == 0) bfadd(acc, ws);
        // 2 straight-line predicated slots (32 edges)
        unsigned k0 = start + g, k1 = start + 16 + g;
        unsigned j0 = (k0 < end) ? csr[k0] : (unsigned)node;
        unsigned j1 = (k1 < end) ? csr[k1] : (unsigned)node;
        uint2 w0 = *(const uint2*)(wfh + (size_t)j0 * 8 + q * 2);
        uint2 w1 = *(const uint2*)(wfh + (size_t)j1 * 8 + q * 2);
        if (k0 < end) bfadd(acc, w0);
        if (k1 < end) bfadd(acc, w1);
        // rare tail for deg > 32
        unsigned k = start + 32 + g;
        for (; k < end; k += 16) {
            unsigned j = csr[k];
            uint2 wv = *(const uint2*)(wfh + (size_t)j * 8 + q * 2);
            bfadd(acc, wv);
        }
        #pragma unroll
        for (int off = 4; off < 64; off <<= 1) {
            acc.x += __shfl_xor(acc.x, off);
            acc.y += __shfl_xor(acc.y, off);
            acc.z += __shfl_xor(acc.z, off);
            acc.w += __shfl_xor(acc.w, off);
        }
        if (g == 0) {
            float4 rv;
            rv.x = iv * acc.x; rv.y = iv * acc.y; rv.z = iv * acc.z; rv.w = iv * acc.w;
            *(float4*)(outh + (size_t)node * D_FEAT + q * 4) = rv;
        }
        cur = nxt;
    }
}

// ---------- fallback (atomic scatter) if workspace too small ----------

__global__ void fb_deg_kernel(const int* __restrict__ dst, float* __restrict__ deg, int E) {
    int i = blockIdx.x * blockDim.x + threadIdx.x;
    int stride = gridDim.x * blockDim.x;
    for (; i < E; i += stride) atomicAdd(&deg[dst[i]], 1.0f);
}
__global__ void fb_inv_kernel(const float* __restrict__ deg, float* __restrict__ inv, int N) {
    int i = blockIdx.x * blockDim.x + threadIdx.x;
    if (i < N) inv[i] = rsqrtf(1.0f + deg[i]);
}
__global__ void fb_scatter_kernel(const float* __restrict__ feat, const int* __restrict__ src,
                                  const int* __restrict__ dst, const float* __restrict__ inv,
                                  float* __restrict__ out, int E) {
    long long tid = (long long)blockIdx.x * blockDim.x + threadIdx.x;
    int e = (int)(tid >> 5);
    int d = (int)(tid & 31);
    if (e >= E) return;
    int s = src[e];
    int t = dst[e];
    atomicAdd(&out[t * D_FEAT + d], inv[s] * feat[s * D_FEAT + d]);
}
__global__ void fb_finalize_kernel(const float* __restrict__ feat, const float* __restrict__ inv,
                                   float* __restrict__ out, int ND) {
    int tid = blockIdx.x * blockDim.x + threadIdx.x;
    if (tid >= ND) return;
    float iv = inv[tid >> 5];
    out[tid] = iv * (out[tid] + iv * feat[tid]);
}

extern "C" void kernel_launch(void* const* d_in, const int* in_sizes, int n_in,
                              void* d_out, int out_size, void* d_ws, size_t ws_size,
                              hipStream_t stream) {
    const float* feat = (const float*)d_in[0];
    const int* esrc = (const int*)d_in[1];
    const int* edst = (const int*)d_in[2];
    float* out = (float*)d_out;

    const int N = in_sizes[0] / D_FEAT;
    const int E = in_sizes[1];
    const int ND = N * D_FEAT;
    const int NR = (N + RS_NODES - 1) >> RSH;

    // capacity-padded per-range segments: mean*1.5 + 256, rounded to 64
    int CAP = (E + NR - 1) / NR;
    CAP = CAP + CAP / 2 + 256;
    CAP = (CAP + 63) & ~63;

    // layout (words): cnt[NR] | binned[NR*CAP] | csr[E] | wf_lo[8N] (16B-align) |
    //                 wf_hi[8N] | ni[2(N+1)] (8B-align)
    size_t binned_off = NR;
    size_t csr_off = binned_off + (size_t)NR * CAP;
    size_t wflo_off = (csr_off + (size_t)E + 3) & ~(size_t)3;
    size_t wfhi_off = wflo_off + 8 * (size_t)N;
    size_t ni_off = (wfhi_off + 8 * (size_t)N + 1) & ~(size_t)1;
    size_t need = (ni_off + 2 * ((size_t)N + 1)) * 4;

    if (ws_size >= need && NR <= NR_PAD && N <= (1 << LOCAL_SHIFT)) {
        unsigned* ws_u   = (unsigned*)d_ws;
        unsigned* cnt    = ws_u;
        unsigned* binned = ws_u + binned_off;
        unsigned* csr    = ws_u + csr_off;
        unsigned* wf_lo  = ws_u + wflo_off;
        unsigned* wf_hi  = ws_u + wfhi_off;
        uint2*    ni     = (uint2*)(ws_u + ni_off);

        hipMemsetAsync(cnt, 0, (size_t)NR * sizeof(unsigned), stream);
        {
            int grid = (E + BF_CHUNK - 1) / BF_CHUNK;
            binfuse_kernel<<<grid, 256, 0, stream>>>(esrc, edst, cnt, binned, E, NR, CAP);
        }
        build_kernel<<<NR, RS_NODES, 0, stream>>>(binned, cnt, feat, wf_lo, wf_hi, csr, ni, N, E, NR, CAP);
        {
            int total_waves = GATHER_BLOCKS * 4;
            int per = (N + total_waves - 1) / total_waves;
            // two serialized passes: each pass's wf half (3.2MB) fits per-XCD L2
            gather_kernel<<<GATHER_BLOCKS, 256, 0, stream>>>(wf_lo, csr, ni, out, N, per);
            gather_kernel<<<GATHER_BLOCKS, 256, 0, stream>>>(wf_hi, csr, ni, out + 16, N, per);
        }
    } else {
        float* deg = (float*)d_ws;
        float* inv = deg + N;
        hipMemsetAsync(deg, 0, (size_t)N * sizeof(float), stream);
        hipMemsetAsync(out, 0, (size_t)ND * sizeof(float), stream);
        {
            int grid = (E + 255) / 256; if (grid > 2048) grid = 2048;
            fb_deg_kernel<<<grid, 256, 0, stream>>>(edst, deg, E);
        }
        fb_inv_kernel<<<(N + 255) / 256, 256, 0, stream>>>(deg, inv, N);
        {
            long long total = (long long)E * D_FEAT;
            fb_scatter_kernel<<<(int)((total + 255) / 256), 256, 0, stream>>>(feat, esrc, edst, inv, out, E);
        }
        fb_finalize_kernel<<<(ND + 255) / 256, 256, 0, stream>>>(feat, inv, out, ND);
    }
}

// Round 14
// 101.782 us; speedup vs baseline: 4.4860x; 1.0238x over previous
//
#include <hip/hip_runtime.h>

#define D_FEAT 32
#define RSH 8              // 256 nodes per range
#define RS_NODES 256
#define LOCAL_SHIFT 24     // pack: src | (dst&255)<<24  (needs N <= 2^24)
#define SRC_MASK 0x00FFFFFFu
#define NR_PAD 512         // scan width / max ranges (N <= 131072)
#define BF_CHUNK 3328      // edges staged per binfuse block
#define GATHER_BLOCKS 2048 // persistent gather grid

// round-to-nearest-even bf16 pack of two floats
__device__ __forceinline__ unsigned bfpack(float lo, float hi) {
    unsigned ul = __float_as_uint(lo), uh = __float_as_uint(hi);
    ul = (ul + 0x7FFFu + ((ul >> 16) & 1u)) >> 16;
    uh = (uh + 0x7FFFu + ((uh >> 16) & 1u)) >> 16;
    return ul | (uh << 16);
}

// accumulate 8 bf16 (one uint4) into two float4 accumulators
__device__ __forceinline__ void bfadd4(float4& a, float4& b, uint4 w) {
    a.x += __uint_as_float(w.x << 16);
    a.y += __uint_as_float(w.x & 0xFFFF0000u);
    a.z += __uint_as_float(w.y << 16);
    a.w += __uint_as_float(w.y & 0xFFFF0000u);
    b.x += __uint_as_float(w.z << 16);
    b.y += __uint_as_float(w.z & 0xFFFF0000u);
    b.z += __uint_as_float(w.w << 16);
    b.w += __uint_as_float(w.w & 0xFFFF0000u);
}

// Fused single-pass binning (r11 proven): stage chunk in LDS, histogram by range,
// reserve per-range space with ONE global atomic per (block,range), place via LDS cursors
// into capacity-padded per-range segments binned[r*CAP ...].
__global__ void binfuse_kernel(const int* __restrict__ src, const int* __restrict__ dst,
                               unsigned* __restrict__ cnt,     // [NR], pre-zeroed
                               unsigned* __restrict__ binned,  // [NR*CAP]
                               int E, int NR, int CAP) {
    __shared__ unsigned sedge[BF_CHUNK];
    __shared__ unsigned short skey[BF_CHUNK];
    __shared__ unsigned hist[NR_PAD];
    __shared__ unsigned base_l[NR_PAD];
    int lo = blockIdx.x * BF_CHUNK;
    int n = min(BF_CHUNK, E - lo);
    if (n <= 0) return;
    for (int i = threadIdx.x; i < NR; i += blockDim.x) hist[i] = 0u;
    __syncthreads();
    for (int i = threadIdx.x; i < n; i += blockDim.x) {
        int s = src[lo + i];
        int d = dst[lo + i];
        sedge[i] = (unsigned)s | ((unsigned)(d & (RS_NODES - 1)) << LOCAL_SHIFT);
        unsigned r = (unsigned)d >> RSH;
        skey[i] = (unsigned short)r;
        atomicAdd(&hist[r], 1u);
    }
    __syncthreads();
    for (int r = threadIdx.x; r < NR; r += blockDim.x) {
        unsigned c = hist[r];
        base_l[r] = c ? atomicAdd(&cnt[r], c) : 0u;
    }
    __syncthreads();
    for (int i = threadIdx.x; i < NR; i += blockDim.x) hist[i] = 0u;
    __syncthreads();
    for (int i = threadIdx.x; i < n; i += blockDim.x) {
        unsigned r = skey[i];
        unsigned off = base_l[r] + atomicAdd(&hist[r], 1u);
        if (off < (unsigned)CAP)  // safety clamp (never triggers with 1.5x+ padding)
            binned[(size_t)r * CAP + off] = sedge[i];
    }
}

// Build per-node CSR within each 256-node range (r11 proven): dense-offset scan over cnt[],
// count -> 256-wide block scan -> place into DENSE csr, emit ni[n]={densestart,inv},
// and convert rows to pre-scaled bf16 wf[n] = bf16(inv[n]*feat[n]) (64B rows).
__global__ void build_kernel(const unsigned* __restrict__ binned, const unsigned* __restrict__ cnt,
                             const float* __restrict__ feat, unsigned* __restrict__ wf,
                             unsigned* __restrict__ csr, uint2* __restrict__ ni,
                             int N, int E, int NR, int CAP) {
    __shared__ unsigned sc[2][NR_PAD];
    __shared__ unsigned deg_l[RS_NODES];
    __shared__ unsigned cur_l[RS_NODES];
    __shared__ float sinv[RS_NODES];
    __shared__ unsigned wtot[4];
    int r = blockIdx.x;
    int tid = threadIdx.x;  // 256
    sc[0][tid]       = (tid < NR)       ? min(cnt[tid], (unsigned)CAP)       : 0u;
    sc[0][tid + 256] = (tid + 256 < NR) ? min(cnt[tid + 256], (unsigned)CAP) : 0u;
    int pin = 0;
    for (int off = 1; off < NR_PAD; off <<= 1) {
        __syncthreads();
        int po = pin ^ 1;
        #pragma unroll
        for (int k = 0; k < 2; k++) {
            int idx = tid + k * 256;
            unsigned x = sc[pin][idx];
            if (idx >= off) x += sc[pin][idx - off];
            sc[po][idx] = x;
        }
        pin ^= 1;
    }
    __syncthreads();
    unsigned dense0 = (r == 0) ? 0u : sc[pin][r - 1];
    unsigned cntr = min(cnt[r], (unsigned)CAP);
    size_t seg = (size_t)r * CAP;
    deg_l[tid] = 0u;
    __syncthreads();
    for (unsigned e = tid; e < cntr; e += RS_NODES)
        atomicAdd(&deg_l[binned[seg + e] >> LOCAL_SHIFT], 1u);
    __syncthreads();
    unsigned d = deg_l[tid];
    int lane = tid & 63, w = tid >> 6;
    unsigned incl = d;
    #pragma unroll
    for (int off = 1; off < 64; off <<= 1) {
        unsigned t = __shfl_up(incl, off, 64);
        if (lane >= off) incl += t;
    }
    if (lane == 63) wtot[w] = incl;
    __syncthreads();
    unsigned woff = 0;
    #pragma unroll
    for (int i = 0; i < 4; i++) if (i < w) woff += wtot[i];
    unsigned base = dense0 + woff + incl - d;
    cur_l[tid] = base;
    float ivv = rsqrtf(1.0f + (float)d);
    sinv[tid] = ivv;
    int node = r * RS_NODES + tid;
    if (node < N) ni[node] = make_uint2(base, __float_as_uint(ivv));
    if (r == 0 && tid == 0) ni[N] = make_uint2((unsigned)E, 0u);
    __syncthreads();
    for (unsigned e = tid; e < cntr; e += RS_NODES) {
        unsigned p = binned[seg + e];
        unsigned pos = atomicAdd(&cur_l[p >> LOCAL_SHIFT], 1u);
        csr[pos] = p & SRC_MASK;
    }
    for (int i = tid; i < RS_NODES * 4; i += RS_NODES) {
        int nl = i >> 2, q = i & 3;
        int nn = r * RS_NODES + nl;
        if (nn < N) {
            float iw = sinv[nl];
            const float4* fp = (const float4*)(feat + (size_t)nn * D_FEAT + q * 8);
            float4 a = fp[0], b = fp[1];
            uint4 o;
            o.x = bfpack(iw * a.x, iw * a.y);
            o.y = bfpack(iw * a.z, iw * a.w);
            o.z = bfpack(iw * b.x, iw * b.y);
            o.w = bfpack(iw * b.z, iw * b.w);
            ((uint4*)wf)[(size_t)nn * 4 + q] = o;
        }
    }
}

// PERSISTENT gather v3: 16 groups x 4 lanes x uint4 -- ONE wf VMEM instr covers 16 edges
// (vs 8 in r10), one csr word per 16 slots. deg<=16 (53%) = 1 slot; deg<=32 under an
// exec-masked branch that fully skips for low-degree nodes. fp32 accumulate.
__global__ void gather_kernel(const unsigned* __restrict__ wf, const unsigned* __restrict__ csr,
                              const uint2* __restrict__ ni, float* __restrict__ out,
                              int N, int per) {
    int w = blockIdx.x * (blockDim.x >> 6) + (threadIdx.x >> 6);
    int lane = threadIdx.x & 63;
    int g = lane >> 2;   // edge group 0..15
    int q = lane & 3;    // dim octet: [8q, 8q+8)
    int n0 = w * per;
    int n1 = min(N, n0 + per);
    if (n0 >= n1) return;
    uint2 cur = ni[n0];
    for (int node = n0; node < n1; ++node) {
        uint2 nxt = ni[node + 1];
        unsigned start = cur.x, end = nxt.x;
        float iv = __uint_as_float(cur.y);
        float4 accA = make_float4(0.f, 0.f, 0.f, 0.f);
        float4 accB = make_float4(0.f, 0.f, 0.f, 0.f);
        // self-loop from wf (bf16 pre-scaled row)
        uint4 ws = *(const uint4*)(wf + (size_t)node * 16 + q * 4);
        if (g == 0) bfadd4(accA, accB, ws);
        // slot 0: 16 edges, branch-free (dummy = own node, hot line)
        unsigned k0 = start + g;
        unsigned j0 = (k0 < end) ? csr[k0] : (unsigned)node;
        uint4 w0 = *(const uint4*)(wf + (size_t)j0 * 16 + q * 4);
        if (k0 < end) bfadd4(accA, accB, w0);
        // slot 1 + rare tail, exec-masked (skips entirely when deg <= 16)
        unsigned k1 = start + 16 + g;
        if (k1 < end) {
            unsigned j1 = csr[k1];
            uint4 w1 = *(const uint4*)(wf + (size_t)j1 * 16 + q * 4);
            bfadd4(accA, accB, w1);
            for (unsigned k = start + 32 + g; k < end; k += 16) {
                unsigned j = csr[k];
                uint4 wv = *(const uint4*)(wf + (size_t)j * 16 + q * 4);
                bfadd4(accA, accB, wv);
            }
        }
        // reduce across 16 groups (lanes q, q+4, ..., q+60)
        #pragma unroll
        for (int off = 4; off < 64; off <<= 1) {
            accA.x += __shfl_xor(accA.x, off);
            accA.y += __shfl_xor(accA.y, off);
            accA.z += __shfl_xor(accA.z, off);
            accA.w += __shfl_xor(accA.w, off);
            accB.x += __shfl_xor(accB.x, off);
            accB.y += __shfl_xor(accB.y, off);
            accB.z += __shfl_xor(accB.z, off);
            accB.w += __shfl_xor(accB.w, off);
        }
        if (g == 0) {
            float4 r0, r1;
            r0.x = iv * accA.x; r0.y = iv * accA.y; r0.z = iv * accA.z; r0.w = iv * accA.w;
            r1.x = iv * accB.x; r1.y = iv * accB.y; r1.z = iv * accB.z; r1.w = iv * accB.w;
            float* o = out + (size_t)node * D_FEAT + q * 8;
            *(float4*)o = r0;
            *(float4*)(o + 4) = r1;
        }
        cur = nxt;
    }
}

// ---------- fallback (atomic scatter) if workspace too small ----------

__global__ void fb_deg_kernel(const int* __restrict__ dst, float* __restrict__ deg, int E) {
    int i = blockIdx.x * blockDim.x + threadIdx.x;
    int stride = gridDim.x * blockDim.x;
    for (; i < E; i += stride) atomicAdd(&deg[dst[i]], 1.0f);
}
__global__ void fb_inv_kernel(const float* __restrict__ deg, float* __restrict__ inv, int N) {
    int i = blockIdx.x * blockDim.x + threadIdx.x;
    if (i < N) inv[i] = rsqrtf(1.0f + deg[i]);
}
__global__ void fb_scatter_kernel(const float* __restrict__ feat, const int* __restrict__ src,
                                  const int* __restrict__ dst, const float* __restrict__ inv,
                                  float* __restrict__ out, int E) {
    long long tid = (long long)blockIdx.x * blockDim.x + threadIdx.x;
    int e = (int)(tid >> 5);
    int d = (int)(tid & 31);
    if (e >= E) return;
    int s = src[e];
    int t = dst[e];
    atomicAdd(&out[t * D_FEAT + d], inv[s] * feat[s * D_FEAT + d]);
}
__global__ void fb_finalize_kernel(const float* __restrict__ feat, const float* __restrict__ inv,
                                   float* __restrict__ out, int ND) {
    int tid = blockIdx.x * blockDim.x + threadIdx.x;
    if (tid >= ND) return;
    float iv = inv[tid >> 5];
    out[tid] = iv * (out[tid] + iv * feat[tid]);
}

extern "C" void kernel_launch(void* const* d_in, const int* in_sizes, int n_in,
                              void* d_out, int out_size, void* d_ws, size_t ws_size,
                              hipStream_t stream) {
    const float* feat = (const float*)d_in[0];
    const int* esrc = (const int*)d_in[1];
    const int* edst = (const int*)d_in[2];
    float* out = (float*)d_out;

    const int N = in_sizes[0] / D_FEAT;
    const int E = in_sizes[1];
    const int ND = N * D_FEAT;
    const int NR = (N + RS_NODES - 1) >> RSH;

    // capacity-padded per-range segments: mean*1.5 + 256, rounded to 64
    int CAP = (E + NR - 1) / NR;
    CAP = CAP + CAP / 2 + 256;
    CAP = (CAP + 63) & ~63;

    // layout (words): cnt[NR] | binned[NR*CAP] | csr[E] | wf[16N] (16B-align) | ni[2(N+1)] (8B-align)
    size_t binned_off = NR;
    size_t csr_off = binned_off + (size_t)NR * CAP;
    size_t wf_off = (csr_off + (size_t)E + 3) & ~(size_t)3;
    size_t ni_off = (wf_off + 16 * (size_t)N + 1) & ~(size_t)1;
    size_t need = (ni_off + 2 * ((size_t)N + 1)) * 4;

    if (ws_size >= need && NR <= NR_PAD && N <= (1 << LOCAL_SHIFT)) {
        unsigned* ws_u   = (unsigned*)d_ws;
        unsigned* cnt    = ws_u;
        unsigned* binned = ws_u + binned_off;
        unsigned* csr    = ws_u + csr_off;
        unsigned* wf     = ws_u + wf_off;
        uint2*    ni     = (uint2*)(ws_u + ni_off);

        hipMemsetAsync(cnt, 0, (size_t)NR * sizeof(unsigned), stream);
        {
            int grid = (E + BF_CHUNK - 1) / BF_CHUNK;
            binfuse_kernel<<<grid, 256, 0, stream>>>(esrc, edst, cnt, binned, E, NR, CAP);
        }
        build_kernel<<<NR, RS_NODES, 0, stream>>>(binned, cnt, feat, wf, csr, ni, N, E, NR, CAP);
        {
            int total_waves = GATHER_BLOCKS * 4;
            int per = (N + total_waves - 1) / total_waves;
            gather_kernel<<<GATHER_BLOCKS, 256, 0, stream>>>(wf, csr, ni, out, N, per);
        }
    } else {
        float* deg = (float*)d_ws;
        float* inv = deg + N;
        hipMemsetAsync(deg, 0, (size_t)N * sizeof(float), stream);
        hipMemsetAsync(out, 0, (size_t)ND * sizeof(float), stream);
        {
            int grid = (E + 255) / 256; if (grid > 2048) grid = 2048;
            fb_deg_kernel<<<grid, 256, 0, stream>>>(edst, deg, E);
        }
        fb_inv_kernel<<<(N + 255) / 256, 256, 0, stream>>>(deg, inv, N);
        {
            long long total = (long long)E * D_FEAT;
            fb_scatter_kernel<<<(int)((total + 255) / 256), 256, 0, stream>>>(feat, esrc, edst, inv, out, E);
        }
        fb_finalize_kernel<<<(ND + 255) / 256, 256, 0, stream>>>(feat, inv, out, ND);
    }
}

// Round 15
// 82.160 us; speedup vs baseline: 5.5574x; 1.2388x over previous
//
#include <hip/hip_runtime.h>

#define D_FEAT 32
#define RSH 8              // 256 nodes per range
#define RS_NODES 256
#define LOCAL_SHIFT 24     // pack: src | (dst&255)<<24  (needs N <= 2^24)
#define SRC_MASK 0x00FFFFFFu
#define MAX_NR 2048
#define NB_BIN 512         // binning blocks
#define SCANA_TR 16        // ranges per scanA block
#define GATHER_BLOCKS 2048 // persistent gather grid

// round-to-nearest-even bf16 pack of two floats
__device__ __forceinline__ unsigned bfpack(float lo, float hi) {
    unsigned ul = __float_as_uint(lo), uh = __float_as_uint(hi);
    ul = (ul + 0x7FFFu + ((ul >> 16) & 1u)) >> 16;
    uh = (uh + 0x7FFFu + ((uh >> 16) & 1u)) >> 16;
    return ul | (uh << 16);
}

__device__ __forceinline__ void bfadd(float4& a, uint2 w) {
    a.x += __uint_as_float(w.x << 16);
    a.y += __uint_as_float(w.x & 0xFFFF0000u);
    a.z += __uint_as_float(w.y << 16);
    a.w += __uint_as_float(w.y & 0xFFFF0000u);
}

// Pass A: per-block LDS histogram of edge chunk by range key (dst>>8). No global atomics.
__global__ void binA_kernel(const int* __restrict__ dst, unsigned* __restrict__ A,
                            int E, int NR, int chunk) {
    __shared__ unsigned cnt[MAX_NR];
    for (int i = threadIdx.x; i < NR; i += blockDim.x) cnt[i] = 0u;
    __syncthreads();
    int b = blockIdx.x;
    int lo = b * chunk;
    int hi = min(lo + chunk, E);
    if (lo < hi) {
        int nq = (hi - lo) >> 2;
        const int4* p = (const int4*)(dst + lo);
        for (int q = threadIdx.x; q < nq; q += blockDim.x) {
            int4 v = p[q];
            atomicAdd(&cnt[v.x >> RSH], 1u);
            atomicAdd(&cnt[v.y >> RSH], 1u);
            atomicAdd(&cnt[v.z >> RSH], 1u);
            atomicAdd(&cnt[v.w >> RSH], 1u);
        }
        for (int i = lo + (nq << 2) + threadIdx.x; i < hi; i += blockDim.x)
            atomicAdd(&cnt[dst[i] >> RSH], 1u);
    }
    __syncthreads();
    for (int i = threadIdx.x; i < NR; i += blockDim.x)
        A[(size_t)b * NR + i] = cnt[i];
}

// Scan 1 (tiled transpose): stage 512 x SCANA_TR tile through LDS, shfl-scan bins.
__global__ void scanA_kernel(unsigned* __restrict__ A, unsigned* __restrict__ keytot, int NR) {
    __shared__ unsigned lds[SCANA_TR * 514];
    int r0 = blockIdx.x * SCANA_TR;
    int tid = threadIdx.x;  // 512 threads
    for (int idx = tid; idx < NB_BIN * SCANA_TR; idx += 512) {
        int c = idx & (SCANA_TR - 1);
        int b = idx >> 4;
        int r = r0 + c;
        lds[c * 514 + b] = (r < NR) ? A[(size_t)b * NR + r] : 0u;
    }
    __syncthreads();
    int wid = tid >> 6;
    int lane = tid & 63;
    #pragma unroll
    for (int cc = 0; cc < 2; cc++) {
        int c = wid * 2 + cc;
        unsigned carry = 0u;
        #pragma unroll
        for (int chunk = 0; chunk < NB_BIN / 64; chunk++) {
            unsigned v = lds[c * 514 + chunk * 64 + lane];
            unsigned incl = v;
            #pragma unroll
            for (int off = 1; off < 64; off <<= 1) {
                unsigned t = __shfl_up(incl, off, 64);
                if (lane >= off) incl += t;
            }
            lds[c * 514 + chunk * 64 + lane] = carry + incl - v;
            carry += __shfl(incl, 63, 64);
        }
        if (lane == 0 && (r0 + c) < NR) keytot[r0 + c] = carry;
    }
    __syncthreads();
    for (int idx = tid; idx < NB_BIN * SCANA_TR; idx += 512) {
        int c = idx & (SCANA_TR - 1);
        int b = idx >> 4;
        int r = r0 + c;
        if (r < NR) A[(size_t)b * NR + r] = lds[c * 514 + b];
    }
}

// Scan 2: exclusive scan of per-range totals -> rs[NR+1]. NR <= 2048.
__global__ void scanR_kernel(const unsigned* __restrict__ keytot, unsigned* __restrict__ rs, int NR) {
    __shared__ unsigned a[2][2048];
    int t = threadIdx.x;
    a[0][t]        = (t < NR)        ? keytot[t]        : 0u;
    a[0][t + 1024] = (t + 1024 < NR) ? keytot[t + 1024] : 0u;
    int pin = 0;
    for (int off = 1; off < 2048; off <<= 1) {
        __syncthreads();
        int po = pin ^ 1;
        #pragma unroll
        for (int k = 0; k < 2; k++) {
            int idx = t + k * 1024;
            unsigned x = a[pin][idx];
            if (idx >= off) x += a[pin][idx - off];
            a[po][idx] = x;
        }
        pin ^= 1;
    }
    __syncthreads();
    #pragma unroll
    for (int k = 0; k < 2; k++) {
        int idx = t + k * 1024;
        if (idx < NR) rs[idx] = idx ? a[pin][idx - 1] : 0u;
    }
    if (t == 0) rs[NR] = a[pin][2047];
}

// Pass B: place packed edge (src | (dst&255)<<24) into range-grouped order via LDS cursors.
__global__ void binB_kernel(const int* __restrict__ src, const int* __restrict__ dst,
                            const unsigned* __restrict__ A, const unsigned* __restrict__ rs,
                            unsigned* __restrict__ binned, int E, int NR, int chunk) {
    __shared__ unsigned cur[MAX_NR];
    int b = blockIdx.x;
    for (int i = threadIdx.x; i < NR; i += blockDim.x)
        cur[i] = rs[i] + A[(size_t)b * NR + i];
    __syncthreads();
    int lo = b * chunk;
    int hi = min(lo + chunk, E);
    if (lo >= hi) return;
    int nq = (hi - lo) >> 2;
    const int4* ps = (const int4*)(src + lo);
    const int4* pd = (const int4*)(dst + lo);
    for (int q = threadIdx.x; q < nq; q += blockDim.x) {
        int4 s = ps[q];
        int4 d = pd[q];
        unsigned p0 = atomicAdd(&cur[d.x >> RSH], 1u);
        binned[p0] = (unsigned)s.x | ((unsigned)(d.x & (RS_NODES - 1)) << LOCAL_SHIFT);
        unsigned p1 = atomicAdd(&cur[d.y >> RSH], 1u);
        binned[p1] = (unsigned)s.y | ((unsigned)(d.y & (RS_NODES - 1)) << LOCAL_SHIFT);
        unsigned p2 = atomicAdd(&cur[d.z >> RSH], 1u);
        binned[p2] = (unsigned)s.z | ((unsigned)(d.z & (RS_NODES - 1)) << LOCAL_SHIFT);
        unsigned p3 = atomicAdd(&cur[d.w >> RSH], 1u);
        binned[p3] = (unsigned)s.w | ((unsigned)(d.w & (RS_NODES - 1)) << LOCAL_SHIFT);
    }
    for (int i = lo + (nq << 2) + threadIdx.x; i < hi; i += blockDim.x) {
        unsigned p = atomicAdd(&cur[dst[i] >> RSH], 1u);
        binned[p] = (unsigned)src[i] | ((unsigned)(dst[i] & (RS_NODES - 1)) << LOCAL_SHIFT);
    }
}

// Build per-node CSR within each 256-node range (count -> 256-wide block scan -> place),
// emit nodeinfo ni[n] = {rowstart, inv-bits}, and convert rows to pre-scaled bf16 wf.
__global__ void build_kernel(const unsigned* __restrict__ binned, const unsigned* __restrict__ rs,
                             const float* __restrict__ feat, unsigned* __restrict__ wf,
                             unsigned* __restrict__ csr, uint2* __restrict__ ni,
                             int N, int E) {
    __shared__ unsigned deg_l[RS_NODES];
    __shared__ unsigned cur_l[RS_NODES];
    __shared__ float sinv[RS_NODES];
    __shared__ unsigned wtot[4];
    int r = blockIdx.x;
    int tid = threadIdx.x;  // 256
    deg_l[tid] = 0u;
    __syncthreads();
    unsigned e0 = rs[r], e1 = rs[r + 1];
    for (unsigned e = e0 + tid; e < e1; e += RS_NODES)
        atomicAdd(&deg_l[binned[e] >> LOCAL_SHIFT], 1u);
    __syncthreads();
    unsigned d = deg_l[tid];
    int lane = tid & 63, w = tid >> 6;
    unsigned incl = d;
    #pragma unroll
    for (int off = 1; off < 64; off <<= 1) {
        unsigned t = __shfl_up(incl, off, 64);
        if (lane >= off) incl += t;
    }
    if (lane == 63) wtot[w] = incl;
    __syncthreads();
    unsigned woff = 0;
    #pragma unroll
    for (int i = 0; i < 4; i++) if (i < w) woff += wtot[i];
    unsigned base = e0 + woff + incl - d;   // exclusive position for node tid
    cur_l[tid] = base;
    float ivv = rsqrtf(1.0f + (float)d);
    sinv[tid] = ivv;
    int node = r * RS_NODES + tid;
    if (node < N) ni[node] = make_uint2(base, __float_as_uint(ivv));
    if (r == 0 && tid == 0) ni[N] = make_uint2((unsigned)E, 0u);
    __syncthreads();
    for (unsigned e = e0 + tid; e < e1; e += RS_NODES) {
        unsigned p = binned[e];
        unsigned pos = atomicAdd(&cur_l[p >> LOCAL_SHIFT], 1u);
        csr[pos] = p & SRC_MASK;
    }
    for (int i = tid; i < RS_NODES * 4; i += RS_NODES) {
        int nl = i >> 2, q = i & 3;
        int nn = r * RS_NODES + nl;
        if (nn < N) {
            float iw = sinv[nl];
            const float4* fp = (const float4*)(feat + (size_t)nn * D_FEAT + q * 8);
            float4 a = fp[0], b = fp[1];
            uint4 o;
            o.x = bfpack(iw * a.x, iw * a.y);
            o.y = bfpack(iw * a.z, iw * a.w);
            o.z = bfpack(iw * b.x, iw * b.y);
            o.w = bfpack(iw * b.z, iw * b.w);
            ((uint4*)wf)[(size_t)nn * 4 + q] = o;
        }
    }
}

// PERSISTENT gather v4: r10 wave shape (8 groups x 8 lanes x uint2, 12-shfl reduce) with
// DUAL-NODE interleaving: two nodes per iteration, all independent loads issued together
// to double memory-level parallelism on the ni->csr->wf dependent chain.
__global__ void gather_kernel(const unsigned* __restrict__ wf, const unsigned* __restrict__ csr,
                              const uint2* __restrict__ ni, float* __restrict__ out,
                              int N, int per) {
    int w = blockIdx.x * (blockDim.x >> 6) + (threadIdx.x >> 6);
    int lane = threadIdx.x & 63;
    int g = lane >> 3;   // edge slot within iteration
    int q = lane & 7;    // dim quad: [4q, 4q+4)
    int n0 = w * per;
    int n1 = min(N, n0 + per);
    if (n0 >= n1) return;
    uint2 curA = ni[n0];
    int node = n0;
    for (; node + 1 < n1; node += 2) {
        uint2 curB = ni[node + 1];
        uint2 nxt  = ni[node + 2];
        unsigned sA = curA.x, eA = curB.x;
        unsigned sB = curB.x, eB = nxt.x;
        float ivA = __uint_as_float(curA.y);
        float ivB = __uint_as_float(curB.y);
        // issue all 4 csr loads (independent)
        unsigned kA0 = sA + g, kA1 = sA + 8 + g;
        unsigned kB0 = sB + g, kB1 = sB + 8 + g;
        unsigned jA0 = (kA0 < eA) ? csr[kA0] : (unsigned)node;
        unsigned jA1 = (kA1 < eA) ? csr[kA1] : (unsigned)node;
        unsigned jB0 = (kB0 < eB) ? csr[kB0] : (unsigned)(node + 1);
        unsigned jB1 = (kB1 < eB) ? csr[kB1] : (unsigned)(node + 1);
        // issue self + 4 wf loads (independent once csr arrives)
        uint2 wsA = *(const uint2*)(wf + (size_t)node * 16 + q * 2);
        uint2 wsB = *(const uint2*)(wf + (size_t)(node + 1) * 16 + q * 2);
        uint2 wA0 = *(const uint2*)(wf + (size_t)jA0 * 16 + q * 2);
        uint2 wA1 = *(const uint2*)(wf + (size_t)jA1 * 16 + q * 2);
        uint2 wB0 = *(const uint2*)(wf + (size_t)jB0 * 16 + q * 2);
        uint2 wB1 = *(const uint2*)(wf + (size_t)jB1 * 16 + q * 2);
        float4 accA = make_float4(0.f, 0.f, 0.f, 0.f);
        float4 accB = make_float4(0.f, 0.f, 0.f, 0.f);
        if (g == 0) bfadd(accA, wsA);
        if (g == 0) bfadd(accB, wsB);
        if (kA0 < eA) bfadd(accA, wA0);
        if (kA1 < eA) bfadd(accA, wA1);
        if (kB0 < eB) bfadd(accB, wB0);
        if (kB1 < eB) bfadd(accB, wB1);
        // rare tails (deg > 16)
        unsigned ka = sA + 16 + g;
        if (ka < eA) {
            for (; ka < eA; ka += 8) {
                unsigned j = csr[ka];
                uint2 wv = *(const uint2*)(wf + (size_t)j * 16 + q * 2);
                bfadd(accA, wv);
            }
        }
        unsigned kb = sB + 16 + g;
        if (kb < eB) {
            for (; kb < eB; kb += 8) {
                unsigned j = csr[kb];
                uint2 wv = *(const uint2*)(wf + (size_t)j * 16 + q * 2);
                bfadd(accB, wv);
            }
        }
        #pragma unroll
        for (int off = 8; off < 64; off <<= 1) {
            accA.x += __shfl_xor(accA.x, off);
            accA.y += __shfl_xor(accA.y, off);
            accA.z += __shfl_xor(accA.z, off);
            accA.w += __shfl_xor(accA.w, off);
            accB.x += __shfl_xor(accB.x, off);
            accB.y += __shfl_xor(accB.y, off);
            accB.z += __shfl_xor(accB.z, off);
            accB.w += __shfl_xor(accB.w, off);
        }
        if (g == 0) {
            float4 rA, rB;
            rA.x = ivA * accA.x; rA.y = ivA * accA.y; rA.z = ivA * accA.z; rA.w = ivA * accA.w;
            rB.x = ivB * accB.x; rB.y = ivB * accB.y; rB.z = ivB * accB.z; rB.w = ivB * accB.w;
            *(float4*)(out + (size_t)node * D_FEAT + q * 4) = rA;
            *(float4*)(out + (size_t)(node + 1) * D_FEAT + q * 4) = rB;
        }
        curA = nxt;
    }
    // odd tail node
    if (node < n1) {
        uint2 nxt = ni[node + 1];
        unsigned start = curA.x, end = nxt.x;
        float iv = __uint_as_float(curA.y);
        float4 acc = make_float4(0.f, 0.f, 0.f, 0.f);
        uint2 ws = *(const uint2*)(wf + (size_t)node * 16 + q * 2);
        if (g == 0) bfadd(acc, ws);
        unsigned k0 = start + g, k1 = start + 8 + g;
        unsigned j0 = (k0 < end) ? csr[k0] : (unsigned)node;
        unsigned j1 = (k1 < end) ? csr[k1] : (unsigned)node;
        uint2 w0 = *(const uint2*)(wf + (size_t)j0 * 16 + q * 2);
        uint2 w1 = *(const uint2*)(wf + (size_t)j1 * 16 + q * 2);
        if (k0 < end) bfadd(acc, w0);
        if (k1 < end) bfadd(acc, w1);
        for (unsigned k = start + 16 + g; k < end; k += 8) {
            unsigned j = csr[k];
            uint2 wv = *(const uint2*)(wf + (size_t)j * 16 + q * 2);
            bfadd(acc, wv);
        }
        #pragma unroll
        for (int off = 8; off < 64; off <<= 1) {
            acc.x += __shfl_xor(acc.x, off);
            acc.y += __shfl_xor(acc.y, off);
            acc.z += __shfl_xor(acc.z, off);
            acc.w += __shfl_xor(acc.w, off);
        }
        if (g == 0) {
            float4 rv;
            rv.x = iv * acc.x; rv.y = iv * acc.y; rv.z = iv * acc.z; rv.w = iv * acc.w;
            *(float4*)(out + (size_t)node * D_FEAT + q * 4) = rv;
        }
    }
}

// ---------- fallback (atomic scatter) if workspace too small ----------

__global__ void fb_deg_kernel(const int* __restrict__ dst, float* __restrict__ deg, int E) {
    int i = blockIdx.x * blockDim.x + threadIdx.x;
    int stride = gridDim.x * blockDim.x;
    for (; i < E; i += stride) atomicAdd(&deg[dst[i]], 1.0f);
}
__global__ void fb_inv_kernel(const float* __restrict__ deg, float* __restrict__ inv, int N) {
    int i = blockIdx.x * blockDim.x + threadIdx.x;
    if (i < N) inv[i] = rsqrtf(1.0f + deg[i]);
}
__global__ void fb_scatter_kernel(const float* __restrict__ feat, const int* __restrict__ src,
                                  const int* __restrict__ dst, const float* __restrict__ inv,
                                  float* __restrict__ out, int E) {
    long long tid = (long long)blockIdx.x * blockDim.x + threadIdx.x;
    int e = (int)(tid >> 5);
    int d = (int)(tid & 31);
    if (e >= E) return;
    int s = src[e];
    int t = dst[e];
    atomicAdd(&out[t * D_FEAT + d], inv[s] * feat[s * D_FEAT + d]);
}
__global__ void fb_finalize_kernel(const float* __restrict__ feat, const float* __restrict__ inv,
                                   float* __restrict__ out, int ND) {
    int tid = blockIdx.x * blockDim.x + threadIdx.x;
    if (tid >= ND) return;
    float iv = inv[tid >> 5];
    out[tid] = iv * (out[tid] + iv * feat[tid]);
}

extern "C" void kernel_launch(void* const* d_in, const int* in_sizes, int n_in,
                              void* d_out, int out_size, void* d_ws, size_t ws_size,
                              hipStream_t stream) {
    const float* feat = (const float*)d_in[0];
    const int* esrc = (const int*)d_in[1];
    const int* edst = (const int*)d_in[2];
    float* out = (float*)d_out;

    const int N = in_sizes[0] / D_FEAT;
    const int E = in_sizes[1];
    const int ND = N * D_FEAT;
    const int NR = (N + RS_NODES - 1) >> RSH;
    const int chunk = (((E + NB_BIN - 1) / NB_BIN) + 3) & ~3;

    size_t wf_off = ((size_t)2 * E + 3) & ~(size_t)3;
    size_t after_rs = wf_off + 16 * (size_t)N + (size_t)NR * NB_BIN + (size_t)NR + (size_t)NR + 1;
    size_t ni_off = (after_rs + 1) & ~(size_t)1;  // 8B-align nodeinfo
    size_t need = (ni_off + 2 * ((size_t)N + 1)) * 4;
    if (ws_size >= need && NR <= MAX_NR && N <= (1 << LOCAL_SHIFT)) {
        unsigned* ws_u     = (unsigned*)d_ws;
        unsigned* binned   = ws_u;
        unsigned* csr      = binned + E;
        unsigned* wf       = ws_u + wf_off;
        unsigned* A        = wf + 16 * (size_t)N;
        unsigned* keytot   = A + (size_t)NR * NB_BIN;
        unsigned* rs       = keytot + NR;
        uint2*    ni       = (uint2*)(ws_u + ni_off);

        binA_kernel<<<NB_BIN, 256, 0, stream>>>(edst, A, E, NR, chunk);
        scanA_kernel<<<(NR + SCANA_TR - 1) / SCANA_TR, 512, 0, stream>>>(A, keytot, NR);
        scanR_kernel<<<1, 1024, 0, stream>>>(keytot, rs, NR);
        binB_kernel<<<NB_BIN, 256, 0, stream>>>(esrc, edst, A, rs, binned, E, NR, chunk);
        build_kernel<<<NR, RS_NODES, 0, stream>>>(binned, rs, feat, wf, csr, ni, N, E);
        {
            int total_waves = GATHER_BLOCKS * 4;
            int per = (N + total_waves - 1) / total_waves;
            gather_kernel<<<GATHER_BLOCKS, 256, 0, stream>>>(wf, csr, ni, out, N, per);
        }
    } else {
        float* deg = (float*)d_ws;
        float* inv = deg + N;
        hipMemsetAsync(deg, 0, (size_t)N * sizeof(float), stream);
        hipMemsetAsync(out, 0, (size_t)ND * sizeof(float), stream);
        {
            int grid = (E + 255) / 256; if (grid > 2048) grid = 2048;
            fb_deg_kernel<<<grid, 256, 0, stream>>>(edst, deg, E);
        }
        fb_inv_kernel<<<(N + 255) / 256, 256, 0, stream>>>(deg, inv, N);
        {
            long long total = (long long)E * D_FEAT;
            fb_scatter_kernel<<<(int)((total + 255) / 256), 256, 0, stream>>>(feat, esrc, edst, inv, out, E);
        }
        fb_finalize_kernel<<<(ND + 255) / 256, 256, 0, stream>>>(feat, inv, out, ND);
    }
}